// Round 16
// baseline (230.439 us; speedup 1.0000x reference)
//
#include <hip/hip_runtime.h>
#include <hip/hip_bf16.h>

typedef short s16b;
using bf16x4 = __attribute__((ext_vector_type(4))) short;
using bf16x8 = __attribute__((ext_vector_type(8))) short;
using f32x4  = __attribute__((ext_vector_type(4))) float;
using u32x4  = __attribute__((ext_vector_type(4))) unsigned;

#define DEVINL __device__ __forceinline__

DEVINL float bf2f(short u) {
    union { float f; unsigned u; } x;
    x.u = ((unsigned)(unsigned short)u) << 16;
    return x.f;
}
DEVINL short f2bf(float f) {   // round-to-nearest-even
    unsigned u = __builtin_bit_cast(unsigned, f);
    u += 0x7FFFu + ((u >> 16) & 1u);
    return (short)(u >> 16);
}
DEVINL unsigned cvtpk(float a, float b) {   // 2xf32 -> packed bf16 (RNE), 1 instr
    unsigned r;
    asm("v_cvt_pk_bf16_f32 %0, %1, %2" : "=v"(r) : "v"(a), "v"(b));
    return r;
}

DEVINL f32x4 mfma16(bf16x8 a, bf16x8 b, f32x4 c) {
    return __builtin_amdgcn_mfma_f32_16x16x32_bf16(a, b, c, 0, 0, 0);
}

DEVINL void gload_lds16(const void* g, void* lds_uniform) {
    __builtin_amdgcn_global_load_lds(
        (const __attribute__((address_space(1))) char*)(const char*)g,
        (__attribute__((address_space(3))) char*)(char*)lds_uniform, 16, 0, 0);
}

// stored position of k within a 32-element K-group:
// chunk order [0-3,16-19,4-7,20-23,8-11,24-27,12-15,28-31]
DEVINL int perm32(int k) {
    return ((k >> 2) & 3) * 8 + ((k >> 4) & 1) * 4 + (k & 3);
}

// LDS frag read, 256B rows, 16 slots of 16B, swizzle slot^=(row&7). One b128.
DEVINL bf16x8 lds256(const s16b* base, int row, int ds, int g) {
    const char* p = (const char*)base + row * 256 + ((((ds << 2) + g) ^ (row & 7)) << 4);
    return *(const bf16x8*)p;
}

// ---------------- merged preprocessing: tables | x-cvt | W transpose-cvt ----------------
__global__ void k_pre2(const float* __restrict__ x, s16b* __restrict__ xb,
                       float* __restrict__ ctab, float* __restrict__ stab,
                       const float* __restrict__ Wqkv, s16b* __restrict__ wqkvt,
                       const float* __restrict__ Wproj, s16b* __restrict__ wprojt) {
    __shared__ float tile[32][33];
    int bid = blockIdx.x;
    if (bid < 512) {
        int idx = bid * 256 + threadIdx.x;      // 2048*64 = 131072
        int i = idx & 63, t = idx >> 6;
        float inv = powf(10000.0f, -(float)i * (1.0f / 64.0f));
        float fr = (float)t * inv;
        ctab[idx] = cosf(fr);
        stab[idx] = sinf(fr);
    } else if (bid < 8704) {
        int idx = (bid - 512) * 256 + threadIdx.x;   // 2097152 threads, 4 elems each
        int p = idx * 4;                              // stored position
        int row = p >> 11, pc = p & 2047;
        int grp = pc >> 5, sp = pc & 31;
        int c = sp >> 3, half = (sp >> 2) & 1;
        int ksrc = grp * 32 + half * 16 + c * 4;      // source k (4 contiguous)
        float4 v = *(const float4*)(x + (size_t)row * 2048 + ksrc);
        bf16x4 o;
        o[0] = f2bf(v.x); o[1] = f2bf(v.y); o[2] = f2bf(v.z); o[3] = f2bf(v.w);
        *(bf16x4*)(xb + (size_t)row * 2048 + pc) = o;
    } else {
        int idx2 = bid - 8704;                       // 16384 blocks = 256 x 64
        int bx = idx2 & 255, by = idx2 >> 8;
        const float* in; s16b* out; int C, c0;
        if (bx < 192) { in = Wqkv; out = wqkvt; C = 6144; c0 = bx * 32; }
        else          { in = Wproj; out = wprojt; C = 2048; c0 = (bx - 192) * 32; }
        int tx = threadIdx.x & 31, ty = threadIdx.x >> 5;   // 32 x 8
        int r0 = by * 32;
#pragma unroll
        for (int kk = 0; kk < 4; ++kk) {
            int r = ty + kk * 8;
            tile[r][tx] = in[(size_t)(r0 + r) * C + c0 + tx];
        }
        __syncthreads();
#pragma unroll
        for (int kk = 0; kk < 4; ++kk) {
            int r = ty + kk * 8;
            out[(size_t)(c0 + r) * 2048 + r0 + perm32(tx)] = f2bf(tile[tx][r]);
        }
    }
}

// ======= Fine-phase tribuf GEMM: BM=128, BN=256, BK=64, 8 waves =======
#define STG_B01(DB, KB)                                                        \
  gload_lds16(srcB + (KB), lds + 49152 + (DB) * 32768 + tid16);                \
  gload_lds16(srcB + 262144 + (KB), lds + 49152 + (DB) * 32768 + 8192 + tid16);
#define STG_B23(DB, KB)                                                        \
  gload_lds16(srcB + 524288 + (KB), lds + 49152 + (DB) * 32768 + 16384 + tid16); \
  gload_lds16(srcB + 786432 + (KB), lds + 49152 + (DB) * 32768 + 24576 + tid16);
#define STG_A01(DB, KB)                                                        \
  gload_lds16(srcA + (KB), lds + (DB) * 16384 + tid16);                        \
  gload_lds16(srcA + 262144 + (KB), lds + (DB) * 16384 + 8192 + tid16);

#define AF_READ(B, KS)                                                         \
    _Pragma("unroll")                                                          \
    for (int fi = 0; fi < 4; ++fi) {                                           \
      int row = (fi >> 1) * 64 + wm * 32 + (fi & 1) * 16 + r15;                \
      af[fi] = *(const bf16x8*)(lds + (B) * 16384 + row * 128                  \
               + ((((KS) * 4 + g) ^ (row & 7)) << 4));                         \
    }

#define PH4(B, KH, JH, STGC, WN)                                               \
  {                                                                            \
    if ((JH) == 0) { AF_READ(B, KH) }                                          \
    _Pragma("unroll")                                                          \
    for (int fj = 0; fj < 2; ++fj) {                                           \
      int row = (JH) * 128 + wn * 32 + fj * 16 + r15;                          \
      bfr[fj] = *(const bf16x8*)(lds + 49152 + (B) * 32768 + row * 128         \
                + ((((KH) * 4 + g) ^ (row & 7)) << 4));                        \
    }                                                                          \
    STGC                                                                       \
    if ((WN) == 6) { asm volatile("s_waitcnt vmcnt(6)" ::: "memory");          \
                     __builtin_amdgcn_sched_barrier(0); }                      \
    else if ((WN) == 0) { asm volatile("s_waitcnt vmcnt(0)" ::: "memory");     \
                     __builtin_amdgcn_sched_barrier(0); }                      \
    __builtin_amdgcn_s_barrier();                                              \
    asm volatile("s_waitcnt lgkmcnt(0)" ::: "memory");                         \
    __builtin_amdgcn_sched_barrier(0);                                         \
    __builtin_amdgcn_s_setprio(1);                                             \
    _Pragma("unroll")                                                          \
    for (int fi = 0; fi < 4; ++fi)                                             \
      _Pragma("unroll")                                                        \
      for (int fj = 0; fj < 2; ++fj)                                           \
        acc[fi][(JH) * 2 + fj] = mfma16(af[fi], bfr[fj], acc[fi][(JH) * 2 + fj]); \
    __builtin_amdgcn_s_setprio(0);                                             \
    __builtin_amdgcn_s_barrier();                                              \
    __builtin_amdgcn_sched_barrier(0);                                         \
  }

#define DO_TILE3(B, S1, S2, S3, WNL)                                           \
    PH4(B, 0, 0, S1, -1)                                                       \
    PH4(B, 0, 1, S2, -1)                                                       \
    PH4(B, 1, 0, S3, -1)                                                       \
    PH4(B, 1, 1, , WNL)

#define GEMM3_MAINLOOP(A_, B_)                                                 \
    __shared__ __attribute__((aligned(16))) char lds[147456];                  \
    const int tid = threadIdx.x;                                               \
    const int lane = tid & 63, wave = tid >> 6;                                \
    const int g = lane >> 4, r15 = lane & 15;                                  \
    const int wm = wave >> 2, wn = wave & 3;                                   \
    const int tid16 = tid << 4;                                                \
    const int rowL = tid16 >> 7;                                               \
    const int swzL = ((((tid16 >> 4) & 7) ^ (rowL & 7)) << 4);                 \
    const char* srcA = (const char*)(A_) + (size_t)(bm + rowL) * 4096 + swzL;  \
    const char* srcB = (const char*)(B_) + (size_t)(bn + rowL) * 4096 + swzL;  \
    f32x4 acc[4][4] = {};                                                      \
    bf16x8 af[4], bfr[2];                                                      \
    STG_B01(0, 0) STG_A01(0, 0) STG_B23(0, 0)                                  \
    STG_B01(1, 128) STG_A01(1, 128) STG_B23(1, 128)                            \
    asm volatile("s_waitcnt vmcnt(6)" ::: "memory");                           \
    __builtin_amdgcn_sched_barrier(0);                                         \
    __builtin_amdgcn_s_barrier();                                              \
    for (int t3 = 0; t3 < 10; ++t3) {                                          \
        const int kb2 = (3 * t3 + 2) * 128;                                    \
        const int kb3 = kb2 + 128, kb4 = kb2 + 256;                            \
        DO_TILE3(0, STG_B01(2, kb2), STG_A01(2, kb2), STG_B23(2, kb2), 6)      \
        DO_TILE3(1, STG_B01(0, kb3), STG_A01(0, kb3), STG_B23(0, kb3), 6)      \
        DO_TILE3(2, STG_B01(1, kb4), STG_A01(1, kb4), STG_B23(1, kb4), 6)      \
    }                                                                          \
    DO_TILE3(0, , , , 0)                                                       \
    DO_TILE3(1, , , , -1)

// QKV GEMM: M=4096 (b*2048+t), N=6144 (which*2048 + h*128 + d). grid 768.
// Epilogue fuses RoPE: Q (pre-scaled by log2e/sqrt(D)) -> Qb plain,
// K -> Kp d-permuted, V -> Vt t-permuted.
__global__ __launch_bounds__(512) void k_gemm_qkv(
    const s16b* __restrict__ A, const s16b* __restrict__ Bt,
    s16b* __restrict__ Qb, s16b* __restrict__ Kp, s16b* __restrict__ Vt,
    const float* __restrict__ ctab, const float* __restrict__ stab) {
    const int bid = blockIdx.x;
    const int xcd = bid & 7, local = bid >> 3;          // local 0..95
    const int rr_ = local >> 5, w = local & 31;
    const int bm = ((xcd & 3) * 8 + (w >> 2)) * 128;
    const int bn = ((xcd >> 2) * 12 + rr_ * 4 + (w & 3)) * 256;
    GEMM3_MAINLOOP(A, Bt)
    const int which = bn >> 11;                          // block-uniform
    if (which < 2) {
        // ---- LDS transpose, then RoPE in registers, then coalesced store ----
        char* sml = (char*)lds;
#pragma unroll
        for (int i = 0; i < 4; ++i) {
#pragma unroll
            for (int j = 0; j < 4; ++j) {
                int mb0 = (i >> 1) * 64 + wm * 32 + (i & 1) * 16 + 4 * g;
                int nn = (j >> 1) * 128 + wn * 32 + (j & 1) * 16 + r15;
#pragma unroll
                for (int e = 0; e < 4; ++e) {
                    int mm = mb0 + e;
                    *(s16b*)(sml + mm * 528 + ((nn * 2) ^ ((mm & 3) << 5))) =
                        f2bf(acc[i][j][e]);
                }
            }
        }
        __syncthreads();
        const int mrow = tid >> 2, c4 = tid & 3;
        const int bb = bm >> 11;
        const int tt = (bm & 2047) + mrow;
        const char* srow = sml + mrow * 528;
        const int sw = (mrow & 3) << 5;
        bf16x8 v[8];
#pragma unroll
        for (int k = 0; k < 8; ++k) {
            int lc = c4 + 4 * k;
            v[k] = *(const bf16x8*)(srow + ((lc * 16) ^ sw));
        }
        float cs[2][8], sn[2][8];
#pragma unroll
        for (int j = 0; j < 2; ++j) {
            int d0 = 8 * c4 + 32 * j;                 // < 64
            const float* cp = ctab + tt * 64 + d0;
            const float* sp = stab + tt * 64 + d0;
            *(float4*)&cs[j][0] = *(const float4*)cp;
            *(float4*)&cs[j][4] = *(const float4*)(cp + 4);
            *(float4*)&sn[j][0] = *(const float4*)sp;
            *(float4*)&sn[j][4] = *(const float4*)(sp + 4);
        }
        if (which == 0) {   // pre-scale Q by log2(e)/sqrt(128): exp2-domain scores
            const float SC = 0.12751744154f;
#pragma unroll
            for (int j = 0; j < 2; ++j)
#pragma unroll
                for (int e = 0; e < 8; ++e) { cs[j][e] *= SC; sn[j][e] *= SC; }
        }
        bf16x8 o[8];
#pragma unroll
        for (int hh = 0; hh < 2; ++hh)
#pragma unroll
            for (int j = 0; j < 2; ++j) {
                int kl = hh * 4 + j, kh = kl + 2;     // d and d+64 chunks
                bf16x8 r1, r2;
#pragma unroll
                for (int e = 0; e < 8; ++e) {
                    float c = cs[j][e], s = sn[j][e];
                    float x1 = bf2f(v[kl][e]), x2 = bf2f(v[kh][e]);
                    r1[e] = f2bf(x1 * c - x2 * s);
                    r2[e] = f2bf(x2 * c + x1 * s);
                }
                o[kl] = r1; o[kh] = r2;
            }
        if (which == 0) {
#pragma unroll
            for (int k = 0; k < 8; ++k) {
                int lc = c4 + 4 * k;
                int ng = bn + lc * 8;
                int h = (ng >> 7) & 15, d = ng & 127;
                *(bf16x8*)(Qb + ((size_t)(bb * 16 + h) * 2048 + tt) * 128 + d) = o[k];
            }
        } else {
#pragma unroll
            for (int k = 0; k < 8; ++k) {
                int lc = c4 + 4 * k;
                int ng = bn + lc * 8;
                int h = (ng >> 7) & 15, d = ng & 127;
                size_t base = ((size_t)(bb * 16 + h) * 2048 + tt) * 128 + (d & ~31);
                int w2 = d & 31;
                bf16x4 lo, hi;
#pragma unroll
                for (int e = 0; e < 4; ++e) { lo[e] = o[k][e]; hi[e] = o[k][e + 4]; }
                *(bf16x4*)(Kp + base + perm32(w2)) = lo;
                *(bf16x4*)(Kp + base + perm32(w2 + 4)) = hi;
            }
        }
    } else {
        // ---- V: [B,H,D,T] t-permuted, bf16x4 writes ----
#pragma unroll
        for (int i = 0; i < 4; ++i) {
            int m0 = bm + (i >> 1) * 64 + wm * 32 + (i & 1) * 16 + 4 * g;
            int b = m0 >> 11, t0 = m0 & 2047;
            int pt = (t0 & ~31) + perm32(t0 & 31);
#pragma unroll
            for (int j = 0; j < 4; ++j) {
                int n = bn + (j >> 1) * 128 + wn * 32 + (j & 1) * 16 + r15;
                int h = (n >> 7) & 15, d = n & 127;
                size_t base = ((size_t)(b * 16 + h) * 128 + d) * 2048 + pt;
                bf16x4 pk;
#pragma unroll
                for (int e = 0; e < 4; ++e) pk[e] = f2bf(acc[i][j][e]);
                *(bf16x4*)(Vt + base) = pk;
            }
        }
    }
}

// Proj GEMM: M=4096, N=2048, fp32 out. grid 256.
__global__ __launch_bounds__(512) void k_gemm_proj(
    const s16b* __restrict__ A, const s16b* __restrict__ Bt, float* __restrict__ Co) {
    const int bid = blockIdx.x;
    const int xcd = bid & 7, local = bid >> 3;          // local 0..31
    const int bm = (xcd * 4 + (local & 3)) * 128;
    const int bn = (local >> 2) * 256;
    GEMM3_MAINLOOP(A, Bt)
#pragma unroll
    for (int i = 0; i < 4; ++i) {
        int m0 = bm + (i >> 1) * 64 + wm * 32 + (i & 1) * 16 + 4 * g;
#pragma unroll
        for (int j = 0; j < 4; ++j) {
            int n = bn + (j >> 1) * 128 + wn * 32 + (j & 1) * 16 + r15;
#pragma unroll
            for (int e = 0; e < 4; ++e) Co[(size_t)(m0 + e) * 2048 + n] = acc[i][j][e];
        }
    }
}

// ---------------- Flash attention: merged hi/lo q-tiles, single pass ----------------
// grid (32 bh, 8 p). One pass over tiles 0..(15-p). Each wave owns 16 rows of
// hi tile (15-p) [qs=0, active every staged tile] AND 16 rows of lo tile (p)
// [qs=1, piggybacks on the same kf/vf frag reads while k0 <= q0l+15].
// vs two-pass: same MFMA work (8x17 wave-tiles), but staged tiles + frag-read
// passes + barrier events drop 17 -> (16-p) (avg 12.5, -26%).
// KVBLK=128, double-buffered 128KB LDS, counted vmcnt(8).
__global__ __launch_bounds__(512) void k_attn(
    const s16b* __restrict__ Qb, const s16b* __restrict__ Kp,
    const s16b* __restrict__ Vt, s16b* __restrict__ AO) {
    __shared__ alignas(16) s16b Ks[2][128 * 128];   // [k][d-perm], 256B rows
    __shared__ alignas(16) s16b Vs[2][128 * 128];   // [d][t-perm], 256B rows
    const int tid = threadIdx.x;
    const int lane = tid & 63, wave = tid >> 6;     // wave 0..7
    const int g = lane >> 4, r15 = lane & 15;
    const int bh = blockIdx.x, pp = blockIdx.y;
    const s16b* Qg = Qb + (size_t)bh * 2048 * 128;
    const char* Kg = (const char*)(Kp + (size_t)bh * 2048 * 128);
    const char* Vg = (const char*)(Vt + (size_t)bh * 128 * 2048);
    const int b = bh >> 4, h = bh & 15;

    const int q0h = (15 - pp) * 128 + wave * 16;    // hi tile rows (qs=0)
    const int q0l = pp * 128 + wave * 16;           // lo tile rows (qs=1)
    const int ktiles = 16 - pp;                     // staged tiles = hi range

#define ASTG(BUF, KT)                                                          \
    {                                                                          \
      const int k0s = (KT) * 128;                                              \
      _Pragma("unroll")                                                        \
      for (int rr = 0; rr < 4; ++rr) {                                         \
        int uo = (rr * 512 + wave * 64) * 16;                                  \
        int o = uo + lane * 16;                                                \
        int row = o >> 8, sl = (o >> 4) & 15;                                  \
        int sg = (sl ^ (row & 7)) << 4;                                        \
        gload_lds16(Kg + (size_t)(k0s + row) * 256 + sg,                       \
                    (char*)Ks + (BUF) * 32768 + uo);                           \
        gload_lds16(Vg + (size_t)row * 4096 + (size_t)k0s * 2 + sg,            \
                    (char*)Vs + (BUF) * 32768 + uo);                           \
      }                                                                        \
    }

    ASTG(0, 0)   // stage tile 0; Q loads overlap it

    bf16x8 qf[2][4];
#pragma unroll
    for (int qs = 0; qs < 2; ++qs) {
        int q0 = qs ? q0l : q0h;
#pragma unroll
        for (int ds = 0; ds < 4; ++ds) {
            const s16b* p = Qg + (size_t)(q0 + r15) * 128 + ds * 32 + 4 * g;
            bf16x4 lo = *(const bf16x4*)p;
            bf16x4 hi = *(const bf16x4*)(p + 16);
            qf[qs][ds] = __builtin_shufflevector(lo, hi, 0, 1, 2, 3, 4, 5, 6, 7);
        }
    }

    f32x4 ot[8][2] = {};               // O^T accs: [dsub][qs]
    float m_s[2] = {-3e38f, -3e38f};
    float l_s[2] = {0.f, 0.f};         // per-lane partials

// online softmax for one qs (exp2 domain, defer-max THR=8)
#define SMAX(QS)                                                               \
    {                                                                          \
        float mx = st[0][QS][0];                                               \
        _Pragma("unroll")                                                      \
        for (int ks = 0; ks < 8; ++ks)                                         \
            _Pragma("unroll")                                                  \
            for (int e = 0; e < 4; ++e)                                        \
                if (ks | e) mx = fmaxf(mx, st[ks][QS][e]);                     \
        mx = fmaxf(mx, __shfl_xor(mx, 16));                                    \
        mx = fmaxf(mx, __shfl_xor(mx, 32));                                    \
        if (__any(mx > m_s[QS] + 8.f)) {                                       \
            float mn = fmaxf(m_s[QS], mx);                                     \
            float sf = exp2f(m_s[QS] - mn);                                    \
            m_s[QS] = mn;                                                      \
            l_s[QS] *= sf;                                                     \
            _Pragma("unroll")                                                  \
            for (int d8 = 0; d8 < 8; ++d8)                                     \
                _Pragma("unroll")                                              \
                for (int e = 0; e < 4; ++e) ot[d8][QS][e] *= sf;               \
        }                                                                      \
        float mm = m_s[QS], sum = 0.f;                                         \
        _Pragma("unroll")                                                      \
        for (int ks = 0; ks < 8; ++ks)                                         \
            _Pragma("unroll")                                                  \
            for (int e = 0; e < 4; ++e) {                                      \
                float p = exp2f(st[ks][QS][e] - mm);                           \
                st[ks][QS][e] = p;                                             \
                sum += p;                                                      \
            }                                                                  \
        l_s[QS] += sum;                                                        \
    }
#define PBQ(QS)                                                                \
    _Pragma("unroll")                                                          \
    for (int k2 = 0; k2 < 4; ++k2) {                                           \
        u32x4 t;                                                               \
        t[0] = cvtpk(st[2 * k2][QS][0], st[2 * k2][QS][1]);                    \
        t[1] = cvtpk(st[2 * k2][QS][2], st[2 * k2][QS][3]);                    \
        t[2] = cvtpk(st[2 * k2 + 1][QS][0], st[2 * k2 + 1][QS][1]);            \
        t[3] = cvtpk(st[2 * k2 + 1][QS][2], st[2 * k2 + 1][QS][3]);            \
        pb[k2][QS] = __builtin_bit_cast(bf16x8, t);                            \
    }

    for (int kt = 0; kt < ktiles; ++kt) {
        const int k0 = kt * 128;
        if (kt + 1 < ktiles) {
            ASTG((kt + 1) & 1, kt + 1)
            asm volatile("s_waitcnt vmcnt(8)" ::: "memory");   // retire tile kt
        } else {
            asm volatile("s_waitcnt vmcnt(0)" ::: "memory");
        }
        __builtin_amdgcn_sched_barrier(0);
        __builtin_amdgcn_s_barrier();
        asm volatile("" ::: "memory");
        __builtin_amdgcn_sched_barrier(0);

        const bool lo_act = (k0 <= q0l + 15);   // wave-uniform
        const s16b* Kb_ = (const s16b*)((const char*)Ks + (kt & 1) * 32768);
        const s16b* Vb_ = (const s16b*)((const char*)Vs + (kt & 1) * 32768);
        // S^T = K . Q^T (exp2-domain, Q pre-scaled); hi always active.
        f32x4 st[8][2] = {};
        __builtin_amdgcn_s_setprio(1);
        if (lo_act) {
#pragma unroll
            for (int ds = 0; ds < 4; ++ds)
#pragma unroll
                for (int ks = 0; ks < 8; ++ks) {
                    bf16x8 kf = lds256(Kb_, ks * 16 + r15, ds, g);
                    st[ks][0] = mfma16(kf, qf[0][ds], st[ks][0]);
                    st[ks][1] = mfma16(kf, qf[1][ds], st[ks][1]);
                }
        } else {
#pragma unroll
            for (int ds = 0; ds < 4; ++ds)
#pragma unroll
                for (int ks = 0; ks < 8; ++ks) {
                    bf16x8 kf = lds256(Kb_, ks * 16 + r15, ds, g);
                    st[ks][0] = mfma16(kf, qf[0][ds], st[ks][0]);
                }
        }
        __builtin_amdgcn_s_setprio(0);
        if (k0 + 127 > q0h) {   // hi diagonal tile
#pragma unroll
            for (int ks = 0; ks < 8; ++ks)
#pragma unroll
                for (int e = 0; e < 4; ++e) {
                    int kk = k0 + ks * 16 + 4 * g + e;
                    if (kk > q0h + r15) st[ks][0][e] = -3e38f;
                }
        }
        if (lo_act && (k0 + 127 > q0l)) {   // lo diagonal tile
#pragma unroll
            for (int ks = 0; ks < 8; ++ks)
#pragma unroll
                for (int e = 0; e < 4; ++e) {
                    int kk = k0 + ks * 16 + 4 * g + e;
                    if (kk > q0l + r15) st[ks][1][e] = -3e38f;
                }
        }
        SMAX(0)
        if (lo_act) { SMAX(1) }
        // P -> bf16 B-frags via v_cvt_pk_bf16_f32
        bf16x8 pb[4][2];
        PBQ(0)
        if (lo_act) { PBQ(1) }
        // O^T += V^T . P^T  (vf shared across qs)
        __builtin_amdgcn_s_setprio(1);
        if (lo_act) {
#pragma unroll
            for (int k2 = 0; k2 < 4; ++k2)
#pragma unroll
                for (int d8 = 0; d8 < 8; ++d8) {
                    bf16x8 vf = lds256(Vb_, d8 * 16 + r15, k2, g);
                    ot[d8][0] = mfma16(vf, pb[k2][0], ot[d8][0]);
                    ot[d8][1] = mfma16(vf, pb[k2][1], ot[d8][1]);
                }
        } else {
#pragma unroll
            for (int k2 = 0; k2 < 4; ++k2)
#pragma unroll
                for (int d8 = 0; d8 < 8; ++d8) {
                    bf16x8 vf = lds256(Vb_, d8 * 16 + r15, k2, g);
                    ot[d8][0] = mfma16(vf, pb[k2][0], ot[d8][0]);
                }
        }
        __builtin_amdgcn_s_setprio(0);
        asm volatile("" ::: "memory");
        __builtin_amdgcn_sched_barrier(0);
        __builtin_amdgcn_s_barrier();   // buf kt&1 reads done before restage
    }
    // write AO [B,T,C] with C-permuted columns (proj GEMM A-operand layout)
#pragma unroll
    for (int qs = 0; qs < 2; ++qs) {
        float l = l_s[qs];
        l += __shfl_xor(l, 16);
        l += __shfl_xor(l, 32);
        float inv = 1.0f / l;
        int q = (qs ? q0l : q0h) + r15;
#pragma unroll
        for (int d8 = 0; d8 < 8; ++d8) {
            uint2 pk2;
            pk2.x = cvtpk(ot[d8][qs][0] * inv, ot[d8][qs][1] * inv);
            pk2.y = cvtpk(ot[d8][qs][2] * inv, ot[d8][qs][3] * inv);
            size_t off = ((size_t)(b * 2048 + q)) * 2048
                       + h * 128 + (d8 >> 1) * 32 + g * 8 + (d8 & 1) * 4;
            *(uint2*)(AO + off) = pk2;
        }
    }
#undef ASTG
#undef SMAX
#undef PBQ
}

extern "C" void kernel_launch(void* const* d_in, const int* in_sizes, int n_in,
                              void* d_out, int out_size, void* d_ws, size_t ws_size,
                              hipStream_t stream) {
    const float* x = (const float*)d_in[0];
    const float* Wqkv = (const float*)d_in[1];
    const float* Wproj = (const float*)d_in[2];
    float* out = (float*)d_out;

    char* ws = (char*)d_ws;
    float* ctab = (float*)ws;
    float* stab = ctab + 2048 * 64;
    size_t off = 1048576;
    s16b* xb = (s16b*)(ws + off); off += 16777216;        // x bf16 K-perm; reused as AO
    s16b* wqkvt = (s16b*)(ws + off); off += 25165824;     // [6144][2048] bf16 K-perm
    s16b* wprojt = (s16b*)(ws + off); off += 8388608;     // [2048][2048] bf16 K-perm
    s16b* Qb = (s16b*)(ws + off); off += 16777216;        // [2,16,2048,128] rope'd+scaled
    s16b* Kp = (s16b*)(ws + off); off += 16777216;        // rope'd K, d-permuted
    s16b* Vt = (s16b*)(ws + off); off += 16777216;        // [2,16,128,2048] t-perm
    s16b* AO = xb;      // alias: xb dead after QKV GEMM

    k_pre2<<<dim3(25088), dim3(256), 0, stream>>>(x, xb, ctab, stab,
                                                  Wqkv, wqkvt, Wproj, wprojt);
    k_gemm_qkv<<<dim3(768), dim3(512), 0, stream>>>(xb, wqkvt, Qb, Kp, Vt, ctab, stab);
    k_attn<<<dim3(32, 8), dim3(512), 0, stream>>>(Qb, Kp, Vt, AO);
    k_gemm_proj<<<dim3(256), dim3(512), 0, stream>>>(AO, wprojt, out);
}

// Round 17
// 228.415 us; speedup vs baseline: 1.0089x; 1.0089x over previous
//
#include <hip/hip_runtime.h>
#include <hip/hip_bf16.h>

typedef short s16b;
using bf16x4 = __attribute__((ext_vector_type(4))) short;
using bf16x8 = __attribute__((ext_vector_type(8))) short;
using f32x4  = __attribute__((ext_vector_type(4))) float;
using u32x4  = __attribute__((ext_vector_type(4))) unsigned;

#define DEVINL __device__ __forceinline__

DEVINL float bf2f(short u) {
    union { float f; unsigned u; } x;
    x.u = ((unsigned)(unsigned short)u) << 16;
    return x.f;
}
DEVINL short f2bf(float f) {   // round-to-nearest-even
    unsigned u = __builtin_bit_cast(unsigned, f);
    u += 0x7FFFu + ((u >> 16) & 1u);
    return (short)(u >> 16);
}
DEVINL unsigned cvtpk(float a, float b) {   // 2xf32 -> packed bf16 (RNE), 1 instr
    unsigned r;
    asm("v_cvt_pk_bf16_f32 %0, %1, %2" : "=v"(r) : "v"(a), "v"(b));
    return r;
}

DEVINL f32x4 mfma16(bf16x8 a, bf16x8 b, f32x4 c) {
    return __builtin_amdgcn_mfma_f32_16x16x32_bf16(a, b, c, 0, 0, 0);
}

DEVINL void gload_lds16(const void* g, void* lds_uniform) {
    __builtin_amdgcn_global_load_lds(
        (const __attribute__((address_space(1))) char*)(const char*)g,
        (__attribute__((address_space(3))) char*)(char*)lds_uniform, 16, 0, 0);
}

// stored position of k within a 32-element K-group:
// chunk order [0-3,16-19,4-7,20-23,8-11,24-27,12-15,28-31]
DEVINL int perm32(int k) {
    return ((k >> 2) & 3) * 8 + ((k >> 4) & 1) * 4 + (k & 3);
}

// LDS frag read, 256B rows, 16 slots of 16B, swizzle slot^=(row&7). One b128.
DEVINL bf16x8 lds256(const s16b* base, int row, int ds, int g) {
    const char* p = (const char*)base + row * 256 + ((((ds << 2) + g) ^ (row & 7)) << 4);
    return *(const bf16x8*)p;
}

// ---------------- merged preprocessing: tables | x-cvt | W transpose-cvt ----------------
__global__ void k_pre2(const float* __restrict__ x, s16b* __restrict__ xb,
                       float* __restrict__ ctab, float* __restrict__ stab,
                       const float* __restrict__ Wqkv, s16b* __restrict__ wqkvt,
                       const float* __restrict__ Wproj, s16b* __restrict__ wprojt) {
    __shared__ float tile[32][33];
    int bid = blockIdx.x;
    if (bid < 512) {
        int idx = bid * 256 + threadIdx.x;      // 2048*64 = 131072
        int i = idx & 63, t = idx >> 6;
        float inv = powf(10000.0f, -(float)i * (1.0f / 64.0f));
        float fr = (float)t * inv;
        ctab[idx] = cosf(fr);
        stab[idx] = sinf(fr);
    } else if (bid < 8704) {
        int idx = (bid - 512) * 256 + threadIdx.x;   // 2097152 threads, 4 elems each
        int p = idx * 4;                              // stored position
        int row = p >> 11, pc = p & 2047;
        int grp = pc >> 5, sp = pc & 31;
        int c = sp >> 3, half = (sp >> 2) & 1;
        int ksrc = grp * 32 + half * 16 + c * 4;      // source k (4 contiguous)
        float4 v = *(const float4*)(x + (size_t)row * 2048 + ksrc);
        bf16x4 o;
        o[0] = f2bf(v.x); o[1] = f2bf(v.y); o[2] = f2bf(v.z); o[3] = f2bf(v.w);
        *(bf16x4*)(xb + (size_t)row * 2048 + pc) = o;
    } else {
        int idx2 = bid - 8704;                       // 16384 blocks = 256 x 64
        int bx = idx2 & 255, by = idx2 >> 8;
        const float* in; s16b* out; int C, c0;
        if (bx < 192) { in = Wqkv; out = wqkvt; C = 6144; c0 = bx * 32; }
        else          { in = Wproj; out = wprojt; C = 2048; c0 = (bx - 192) * 32; }
        int tx = threadIdx.x & 31, ty = threadIdx.x >> 5;   // 32 x 8
        int r0 = by * 32;
#pragma unroll
        for (int kk = 0; kk < 4; ++kk) {
            int r = ty + kk * 8;
            tile[r][tx] = in[(size_t)(r0 + r) * C + c0 + tx];
        }
        __syncthreads();
#pragma unroll
        for (int kk = 0; kk < 4; ++kk) {
            int r = ty + kk * 8;
            out[(size_t)(c0 + r) * 2048 + r0 + perm32(tx)] = f2bf(tile[tx][r]);
        }
    }
}

// ======= Fine-phase tribuf GEMM: BM=128, BN=256, BK=64, 8 waves =======
#define STG_B01(DB, KB)                                                        \
  gload_lds16(srcB + (KB), lds + 49152 + (DB) * 32768 + tid16);                \
  gload_lds16(srcB + 262144 + (KB), lds + 49152 + (DB) * 32768 + 8192 + tid16);
#define STG_B23(DB, KB)                                                        \
  gload_lds16(srcB + 524288 + (KB), lds + 49152 + (DB) * 32768 + 16384 + tid16); \
  gload_lds16(srcB + 786432 + (KB), lds + 49152 + (DB) * 32768 + 24576 + tid16);
#define STG_A01(DB, KB)                                                        \
  gload_lds16(srcA + (KB), lds + (DB) * 16384 + tid16);                        \
  gload_lds16(srcA + 262144 + (KB), lds + (DB) * 16384 + 8192 + tid16);

#define AF_READ(B, KS)                                                         \
    _Pragma("unroll")                                                          \
    for (int fi = 0; fi < 4; ++fi) {                                           \
      int row = (fi >> 1) * 64 + wm * 32 + (fi & 1) * 16 + r15;                \
      af[fi] = *(const bf16x8*)(lds + (B) * 16384 + row * 128                  \
               + ((((KS) * 4 + g) ^ (row & 7)) << 4));                         \
    }

#define PH4(B, KH, JH, STGC, WN)                                               \
  {                                                                            \
    if ((JH) == 0) { AF_READ(B, KH) }                                          \
    _Pragma("unroll")                                                          \
    for (int fj = 0; fj < 2; ++fj) {                                           \
      int row = (JH) * 128 + wn * 32 + fj * 16 + r15;                          \
      bfr[fj] = *(const bf16x8*)(lds + 49152 + (B) * 32768 + row * 128         \
                + ((((KH) * 4 + g) ^ (row & 7)) << 4));                        \
    }                                                                          \
    STGC                                                                       \
    if ((WN) == 6) { asm volatile("s_waitcnt vmcnt(6)" ::: "memory");          \
                     __builtin_amdgcn_sched_barrier(0); }                      \
    else if ((WN) == 0) { asm volatile("s_waitcnt vmcnt(0)" ::: "memory");     \
                     __builtin_amdgcn_sched_barrier(0); }                      \
    __builtin_amdgcn_s_barrier();                                              \
    asm volatile("s_waitcnt lgkmcnt(0)" ::: "memory");                         \
    __builtin_amdgcn_sched_barrier(0);                                         \
    __builtin_amdgcn_s_setprio(1);                                             \
    _Pragma("unroll")                                                          \
    for (int fi = 0; fi < 4; ++fi)                                             \
      _Pragma("unroll")                                                        \
      for (int fj = 0; fj < 2; ++fj)                                           \
        acc[fi][(JH) * 2 + fj] = mfma16(af[fi], bfr[fj], acc[fi][(JH) * 2 + fj]); \
    __builtin_amdgcn_s_setprio(0);                                             \
    __builtin_amdgcn_s_barrier();                                              \
    __builtin_amdgcn_sched_barrier(0);                                         \
  }

#define DO_TILE3(B, S1, S2, S3, WNL)                                           \
    PH4(B, 0, 0, S1, -1)                                                       \
    PH4(B, 0, 1, S2, -1)                                                       \
    PH4(B, 1, 0, S3, -1)                                                       \
    PH4(B, 1, 1, , WNL)

#define GEMM3_MAINLOOP(A_, B_)                                                 \
    __shared__ __attribute__((aligned(16))) char lds[147456];                  \
    const int tid = threadIdx.x;                                               \
    const int lane = tid & 63, wave = tid >> 6;                                \
    const int g = lane >> 4, r15 = lane & 15;                                  \
    const int wm = wave >> 2, wn = wave & 3;                                   \
    const int tid16 = tid << 4;                                                \
    const int rowL = tid16 >> 7;                                               \
    const int swzL = ((((tid16 >> 4) & 7) ^ (rowL & 7)) << 4);                 \
    const char* srcA = (const char*)(A_) + (size_t)(bm + rowL) * 4096 + swzL;  \
    const char* srcB = (const char*)(B_) + (size_t)(bn + rowL) * 4096 + swzL;  \
    f32x4 acc[4][4] = {};                                                      \
    bf16x8 af[4], bfr[2];                                                      \
    STG_B01(0, 0) STG_A01(0, 0) STG_B23(0, 0)                                  \
    STG_B01(1, 128) STG_A01(1, 128) STG_B23(1, 128)                            \
    asm volatile("s_waitcnt vmcnt(6)" ::: "memory");                           \
    __builtin_amdgcn_sched_barrier(0);                                         \
    __builtin_amdgcn_s_barrier();                                              \
    for (int t3 = 0; t3 < 10; ++t3) {                                          \
        const int kb2 = (3 * t3 + 2) * 128;                                    \
        const int kb3 = kb2 + 128, kb4 = kb2 + 256;                            \
        DO_TILE3(0, STG_B01(2, kb2), STG_A01(2, kb2), STG_B23(2, kb2), 6)      \
        DO_TILE3(1, STG_B01(0, kb3), STG_A01(0, kb3), STG_B23(0, kb3), 6)      \
        DO_TILE3(2, STG_B01(1, kb4), STG_A01(1, kb4), STG_B23(1, kb4), 6)      \
    }                                                                          \
    DO_TILE3(0, , , , 0)                                                       \
    DO_TILE3(1, , , , -1)

// QKV GEMM: M=4096 (b*2048+t), N=6144 (which*2048 + h*128 + d). grid 768.
// Epilogue fuses RoPE: Q (pre-scaled by log2e/sqrt(D)) -> Qb plain,
// K -> Kp d-permuted, V -> Vt t-permuted.
__global__ __launch_bounds__(512) void k_gemm_qkv(
    const s16b* __restrict__ A, const s16b* __restrict__ Bt,
    s16b* __restrict__ Qb, s16b* __restrict__ Kp, s16b* __restrict__ Vt,
    const float* __restrict__ ctab, const float* __restrict__ stab) {
    const int bid = blockIdx.x;
    const int xcd = bid & 7, local = bid >> 3;          // local 0..95
    const int rr_ = local >> 5, w = local & 31;
    const int bm = ((xcd & 3) * 8 + (w >> 2)) * 128;
    const int bn = ((xcd >> 2) * 12 + rr_ * 4 + (w & 3)) * 256;
    GEMM3_MAINLOOP(A, Bt)
    const int which = bn >> 11;                          // block-uniform
    if (which < 2) {
        // ---- LDS transpose, then RoPE in registers, then coalesced store ----
        char* sml = (char*)lds;
#pragma unroll
        for (int i = 0; i < 4; ++i) {
#pragma unroll
            for (int j = 0; j < 4; ++j) {
                int mb0 = (i >> 1) * 64 + wm * 32 + (i & 1) * 16 + 4 * g;
                int nn = (j >> 1) * 128 + wn * 32 + (j & 1) * 16 + r15;
#pragma unroll
                for (int e = 0; e < 4; ++e) {
                    int mm = mb0 + e;
                    *(s16b*)(sml + mm * 528 + ((nn * 2) ^ ((mm & 3) << 5))) =
                        f2bf(acc[i][j][e]);
                }
            }
        }
        __syncthreads();
        const int mrow = tid >> 2, c4 = tid & 3;
        const int bb = bm >> 11;
        const int tt = (bm & 2047) + mrow;
        const char* srow = sml + mrow * 528;
        const int sw = (mrow & 3) << 5;
        bf16x8 v[8];
#pragma unroll
        for (int k = 0; k < 8; ++k) {
            int lc = c4 + 4 * k;
            v[k] = *(const bf16x8*)(srow + ((lc * 16) ^ sw));
        }
        float cs[2][8], sn[2][8];
#pragma unroll
        for (int j = 0; j < 2; ++j) {
            int d0 = 8 * c4 + 32 * j;                 // < 64
            const float* cp = ctab + tt * 64 + d0;
            const float* sp = stab + tt * 64 + d0;
            *(float4*)&cs[j][0] = *(const float4*)cp;
            *(float4*)&cs[j][4] = *(const float4*)(cp + 4);
            *(float4*)&sn[j][0] = *(const float4*)sp;
            *(float4*)&sn[j][4] = *(const float4*)(sp + 4);
        }
        if (which == 0) {   // pre-scale Q by log2(e)/sqrt(128): exp2-domain scores
            const float SC = 0.12751744154f;
#pragma unroll
            for (int j = 0; j < 2; ++j)
#pragma unroll
                for (int e = 0; e < 8; ++e) { cs[j][e] *= SC; sn[j][e] *= SC; }
        }
        bf16x8 o[8];
#pragma unroll
        for (int hh = 0; hh < 2; ++hh)
#pragma unroll
            for (int j = 0; j < 2; ++j) {
                int kl = hh * 4 + j, kh = kl + 2;     // d and d+64 chunks
                bf16x8 r1, r2;
#pragma unroll
                for (int e = 0; e < 8; ++e) {
                    float c = cs[j][e], s = sn[j][e];
                    float x1 = bf2f(v[kl][e]), x2 = bf2f(v[kh][e]);
                    r1[e] = f2bf(x1 * c - x2 * s);
                    r2[e] = f2bf(x2 * c + x1 * s);
                }
                o[kl] = r1; o[kh] = r2;
            }
        if (which == 0) {
#pragma unroll
            for (int k = 0; k < 8; ++k) {
                int lc = c4 + 4 * k;
                int ng = bn + lc * 8;
                int h = (ng >> 7) & 15, d = ng & 127;
                *(bf16x8*)(Qb + ((size_t)(bb * 16 + h) * 2048 + tt) * 128 + d) = o[k];
            }
        } else {
#pragma unroll
            for (int k = 0; k < 8; ++k) {
                int lc = c4 + 4 * k;
                int ng = bn + lc * 8;
                int h = (ng >> 7) & 15, d = ng & 127;
                size_t base = ((size_t)(bb * 16 + h) * 2048 + tt) * 128 + (d & ~31);
                int w2 = d & 31;
                bf16x4 lo, hi;
#pragma unroll
                for (int e = 0; e < 4; ++e) { lo[e] = o[k][e]; hi[e] = o[k][e + 4]; }
                *(bf16x4*)(Kp + base + perm32(w2)) = lo;
                *(bf16x4*)(Kp + base + perm32(w2 + 4)) = hi;
            }
        }
    } else {
        // ---- V: [B,H,D,T] t-permuted, bf16x4 writes ----
#pragma unroll
        for (int i = 0; i < 4; ++i) {
            int m0 = bm + (i >> 1) * 64 + wm * 32 + (i & 1) * 16 + 4 * g;
            int b = m0 >> 11, t0 = m0 & 2047;
            int pt = (t0 & ~31) + perm32(t0 & 31);
#pragma unroll
            for (int j = 0; j < 4; ++j) {
                int n = bn + (j >> 1) * 128 + wn * 32 + (j & 1) * 16 + r15;
                int h = (n >> 7) & 15, d = n & 127;
                size_t base = ((size_t)(b * 16 + h) * 128 + d) * 2048 + pt;
                bf16x4 pk;
#pragma unroll
                for (int e = 0; e < 4; ++e) pk[e] = f2bf(acc[i][j][e]);
                *(bf16x4*)(Vt + base) = pk;
            }
        }
    }
}

// Proj GEMM: M=4096, N=2048, fp32 out. grid 256.
__global__ __launch_bounds__(512) void k_gemm_proj(
    const s16b* __restrict__ A, const s16b* __restrict__ Bt, float* __restrict__ Co) {
    const int bid = blockIdx.x;
    const int xcd = bid & 7, local = bid >> 3;          // local 0..31
    const int bm = (xcd * 4 + (local & 3)) * 128;
    const int bn = (local >> 2) * 256;
    GEMM3_MAINLOOP(A, Bt)
#pragma unroll
    for (int i = 0; i < 4; ++i) {
        int m0 = bm + (i >> 1) * 64 + wm * 32 + (i & 1) * 16 + 4 * g;
#pragma unroll
        for (int j = 0; j < 4; ++j) {
            int n = bn + (j >> 1) * 128 + wn * 32 + (j & 1) * 16 + r15;
#pragma unroll
            for (int e = 0; e < 4; ++e) Co[(size_t)(m0 + e) * 2048 + n] = acc[i][j][e];
        }
    }
}

// ---------------- Flash attention: KVBLK=128, 8 waves (2/SIMD), 16 q-rows/wave ----------------
// grid (32 bh, 8 p): block does q-tiles (15-p) then (p): 17 staged K-tiles per
// block -> perfectly balanced. Double-buffered 128KB LDS, counted vmcnt(8).
__global__ __launch_bounds__(512) void k_attn(
    const s16b* __restrict__ Qb, const s16b* __restrict__ Kp,
    const s16b* __restrict__ Vt, s16b* __restrict__ AO) {
    __shared__ alignas(16) s16b Ks[2][128 * 128];   // [k][d-perm], 256B rows, 32KB each
    __shared__ alignas(16) s16b Vs[2][128 * 128];   // [d][t-perm], 256B rows, 32KB each
    const int tid = threadIdx.x;
    const int lane = tid & 63, wave = tid >> 6;     // wave 0..7
    const int g = lane >> 4, r15 = lane & 15;
    const int bh = blockIdx.x, pp = blockIdx.y;
    const s16b* Qg = Qb + (size_t)bh * 2048 * 128;
    const char* Kg = (const char*)(Kp + (size_t)bh * 2048 * 128);
    const char* Vg = (const char*)(Vt + (size_t)bh * 128 * 2048);
    const int b = bh >> 4, h = bh & 15;

#define ASTG(BUF, KT)                                                          \
    {                                                                          \
      const int k0s = (KT) * 128;                                              \
      _Pragma("unroll")                                                        \
      for (int rr = 0; rr < 4; ++rr) {                                         \
        int uo = (rr * 512 + wave * 64) * 16;                                  \
        int o = uo + lane * 16;                                                \
        int row = o >> 8, sl = (o >> 4) & 15;                                  \
        int sg = (sl ^ (row & 7)) << 4;                                        \
        gload_lds16(Kg + (size_t)(k0s + row) * 256 + sg,                       \
                    (char*)Ks + (BUF) * 32768 + uo);                           \
        gload_lds16(Vg + (size_t)row * 4096 + (size_t)k0s * 2 + sg,            \
                    (char*)Vs + (BUF) * 32768 + uo);                           \
      }                                                                        \
    }

    for (int pass = 0; pass < 2; ++pass) {
        const int qt = pass ? pp : (15 - pp);
        const int q0 = qt * 128 + wave * 16;       // 16 q-rows per wave
        const int ktiles = qt + 1;                 // 128-wide K tiles

        ASTG(0, 0)   // stage tile 0; Q loads overlap it

        bf16x8 qf[4];
#pragma unroll
        for (int ds = 0; ds < 4; ++ds) {
            const s16b* p = Qg + (size_t)(q0 + r15) * 128 + ds * 32 + 4 * g;
            bf16x4 lo = *(const bf16x4*)p;
            bf16x4 hi = *(const bf16x4*)(p + 16);
            qf[ds] = __builtin_shufflevector(lo, hi, 0, 1, 2, 3, 4, 5, 6, 7);
        }

        f32x4 ot[8] = {};                  // O^T accs per dsub
        float m_s = -3e38f;
        float l_s = 0.f;                   // per-lane partial

        for (int kt = 0; kt < ktiles; ++kt) {
            const int k0 = kt * 128;
            if (kt + 1 < ktiles) {
                ASTG((kt + 1) & 1, kt + 1)
                asm volatile("s_waitcnt vmcnt(8)" ::: "memory");   // retire tile kt
            } else {
                asm volatile("s_waitcnt vmcnt(0)" ::: "memory");
            }
            __builtin_amdgcn_sched_barrier(0);
            __builtin_amdgcn_s_barrier();
            asm volatile("" ::: "memory");
            __builtin_amdgcn_sched_barrier(0);

            if (k0 <= q0 + 15) {   // wave-uniform causal skip
                const s16b* Kb_ = (const s16b*)((const char*)Ks + (kt & 1) * 32768);
                const s16b* Vb_ = (const s16b*)((const char*)Vs + (kt & 1) * 32768);
                // S^T = K . Q^T (exp2-domain, Q pre-scaled). 32 MFMA.
                f32x4 st[8] = {};
                __builtin_amdgcn_s_setprio(1);
#pragma unroll
                for (int ds = 0; ds < 4; ++ds) {
#pragma unroll
                    for (int ks = 0; ks < 8; ++ks) {
                        bf16x8 kf = lds256(Kb_, ks * 16 + r15, ds, g);
                        st[ks] = mfma16(kf, qf[ds], st[ks]);
                    }
                }
                __builtin_amdgcn_s_setprio(0);
                if (k0 + 127 > q0) {   // diagonal tile only: causal mask
#pragma unroll
                    for (int ks = 0; ks < 8; ++ks)
#pragma unroll
                        for (int e = 0; e < 4; ++e) {
                            int kk = k0 + ks * 16 + 4 * g + e;
                            int qq = q0 + r15;
                            if (kk > qq) st[ks][e] = -3e38f;
                        }
                }
                // online softmax (exp2 domain, defer-max THR=8)
                {
                    float mx = st[0][0];
#pragma unroll
                    for (int ks = 0; ks < 8; ++ks)
#pragma unroll
                        for (int e = 0; e < 4; ++e)
                            if (ks | e) mx = fmaxf(mx, st[ks][e]);
                    mx = fmaxf(mx, __shfl_xor(mx, 16));
                    mx = fmaxf(mx, __shfl_xor(mx, 32));
                    if (__any(mx > m_s + 8.f)) {     // rescale only when needed
                        float mn = fmaxf(m_s, mx);
                        float sf = exp2f(m_s - mn);
                        m_s = mn;
                        l_s *= sf;
#pragma unroll
                        for (int d8 = 0; d8 < 8; ++d8)
#pragma unroll
                            for (int e = 0; e < 4; ++e) ot[d8][e] *= sf;
                    }
                    float mm = m_s, sum = 0.f;
#pragma unroll
                    for (int ks = 0; ks < 8; ++ks)
#pragma unroll
                        for (int e = 0; e < 4; ++e) {
                            float p = exp2f(st[ks][e] - mm);
                            st[ks][e] = p;
                            sum += p;
                        }
                    l_s += sum;
                }
                // P -> bf16 B-frags via v_cvt_pk_bf16_f32
                bf16x8 pb[4];
#pragma unroll
                for (int k2 = 0; k2 < 4; ++k2) {
                    u32x4 t;
                    t[0] = cvtpk(st[2 * k2][0], st[2 * k2][1]);
                    t[1] = cvtpk(st[2 * k2][2], st[2 * k2][3]);
                    t[2] = cvtpk(st[2 * k2 + 1][0], st[2 * k2 + 1][1]);
                    t[3] = cvtpk(st[2 * k2 + 1][2], st[2 * k2 + 1][3]);
                    pb[k2] = __builtin_bit_cast(bf16x8, t);
                }
                // O^T += V^T . P^T   (32 MFMA)
                __builtin_amdgcn_s_setprio(1);
#pragma unroll
                for (int k2 = 0; k2 < 4; ++k2)
#pragma unroll
                    for (int d8 = 0; d8 < 8; ++d8) {
                        bf16x8 vf = lds256(Vb_, d8 * 16 + r15, k2, g);
                        ot[d8] = mfma16(vf, pb[k2], ot[d8]);
                    }
                __builtin_amdgcn_s_setprio(0);
            }
            asm volatile("" ::: "memory");
            __builtin_amdgcn_sched_barrier(0);
            __builtin_amdgcn_s_barrier();   // buf kt&1 reads done before restage
        }
        // write AO [B,T,C] with C-permuted columns (proj GEMM A-operand layout)
        {
            float l = l_s;
            l += __shfl_xor(l, 16);
            l += __shfl_xor(l, 32);
            float inv = 1.0f / l;
            int q = q0 + r15;
#pragma unroll
            for (int d8 = 0; d8 < 8; ++d8) {
                uint2 pk2;
                pk2.x = cvtpk(ot[d8][0] * inv, ot[d8][1] * inv);
                pk2.y = cvtpk(ot[d8][2] * inv, ot[d8][3] * inv);
                size_t off = ((size_t)(b * 2048 + q)) * 2048
                           + h * 128 + (d8 >> 1) * 32 + g * 8 + (d8 & 1) * 4;
                *(uint2*)(AO + off) = pk2;
            }
        }
    }
#undef ASTG
}

extern "C" void kernel_launch(void* const* d_in, const int* in_sizes, int n_in,
                              void* d_out, int out_size, void* d_ws, size_t ws_size,
                              hipStream_t stream) {
    const float* x = (const float*)d_in[0];
    const float* Wqkv = (const float*)d_in[1];
    const float* Wproj = (const float*)d_in[2];
    float* out = (float*)d_out;

    char* ws = (char*)d_ws;
    float* ctab = (float*)ws;
    float* stab = ctab + 2048 * 64;
    size_t off = 1048576;
    s16b* xb = (s16b*)(ws + off); off += 16777216;        // x bf16 K-perm; reused as AO
    s16b* wqkvt = (s16b*)(ws + off); off += 25165824;     // [6144][2048] bf16 K-perm
    s16b* wprojt = (s16b*)(ws + off); off += 8388608;     // [2048][2048] bf16 K-perm
    s16b* Qb = (s16b*)(ws + off); off += 16777216;        // [2,16,2048,128] rope'd+scaled
    s16b* Kp = (s16b*)(ws + off); off += 16777216;        // rope'd K, d-permuted
    s16b* Vt = (s16b*)(ws + off); off += 16777216;        // [2,16,128,2048] t-perm
    s16b* AO = xb;      // alias: xb dead after QKV GEMM

    k_pre2<<<dim3(25088), dim3(256), 0, stream>>>(x, xb, ctab, stab,
                                                  Wqkv, wqkvt, Wproj, wprojt);
    k_gemm_qkv<<<dim3(768), dim3(512), 0, stream>>>(xb, wqkvt, Qb, Kp, Vt, ctab, stab);
    k_attn<<<dim3(32, 8), dim3(512), 0, stream>>>(Qb, Kp, Vt, AO);
    k_gemm_proj<<<dim3(256), dim3(512), 0, stream>>>(AO, wprojt, out);
}